// Round 5
// baseline (528.626 us; speedup 1.0000x reference)
//
#include <hip/hip_runtime.h>

// Slot Attention fwd, B=8 N=2048 D=256 S=8 H=256 ITERS=3.  All f32.
// Single persistent kernel (plain launch); phases separated by a software
// grid barrier (same construction as ROCm's ockl grid sync).
//   Pg[s] = diag(g_in[s]) * Wk[s]^T Wq[s]   (iteration-invariant, phase A1)
//   qg[b,s] = Pg[s]*sn[b,s] + qcon[s],  qc[b,s] = sn.vq[s] + c0[s]
//   dots[b,s,n] = SCALE*( xn[b,n,:].qg[b,s,:] + qc[b,s] )
//   updates[b,s,o] = (sum_d axun*g_in*Wv)/rowsum + cv[s,o]
// xn = LN(inputs) recomputed on the fly in the dots phase (never stored).

#define BB 8
#define NT 2048
#define DD 256
#define SS 8
#define HH 256
#define GRID 256

static constexpr float F_EPS   = 1e-8f;
static constexpr float F_LNEPS = 1e-5f;
static constexpr float F_SCALE = 0.0625f;   // 256^-0.5

__device__ __forceinline__ float wredsum(float v) {
#pragma unroll
  for (int m = 32; m > 0; m >>= 1) v += __shfl_xor(v, m, 64);
  return v;
}
__device__ __forceinline__ float sigm(float x) { return 1.f / (1.f + __expf(-x)); }
__device__ __forceinline__ float tanhfast(float x) {
  float ax = fabsf(x);
  float e = __expf(2.f * ax);
  float t2 = 1.f - 2.f / (e + 1.f);
  return x < 0.f ? -t2 : t2;
}
// X2 LDS layout: (b,d) -> b*288 + (d>>5)*36 + (d&31)   (bank-conflict-free)
__device__ __forceinline__ int x2i(int bb, int dd) { return bb*288 + (dd>>5)*36 + (dd&31); }

// software grid barrier: counter zeroed by hipMemsetAsync before each launch.
__device__ __forceinline__ void gbar(int* bar, int target) {
  __syncthreads();
  if (threadIdx.x == 0) {
    __threadfence();   // release (agent scope: L2 writeback on gfx950)
    __hip_atomic_fetch_add(bar, 1, __ATOMIC_RELAXED, __HIP_MEMORY_SCOPE_AGENT);
    while (__hip_atomic_load(bar, __ATOMIC_RELAXED, __HIP_MEMORY_SCOPE_AGENT) < target)
      __builtin_amdgcn_s_sleep(2);
    __threadfence();   // acquire (cache invalidate)
  }
  __syncthreads();
}

struct P {
  const float *inputs,*noise,*smu,*slsig,*g_in,*b_in,*g_ns,*b_ns,*g_pf,*b_pf;
  const float *Wq,*bq,*Wk,*bk,*Wv,*bv,*Wih,*bih,*Whh,*bhh,*W1,*b1,*W2,*b2;
  float *slots,*smid,*ck,*cv,*qg,*qc,*rsum,*axun,*upd,*ghb,*h1b,*vq,*qcon,*c0,*Pg;
  float *out_slots,*out_attn;
  int *bar;
};

template <typename F>
__device__ __forceinline__ void gemv32(const float* __restrict__ Wrow0,
                                       const float* __restrict__ X2,
                                       float* __restrict__ part, F emit) {
  int t = threadIdx.x;
  int ol = t >> 3, dg = t & 7;
  const float4* wr = (const float4*)(Wrow0 + (size_t)ol*256 + (size_t)dg*32);
  __syncthreads();                 // X2 staged / part free
  float acc[8] = {0.f,0.f,0.f,0.f,0.f,0.f,0.f,0.f};
#pragma unroll
  for (int j = 0; j < 8; ++j) {
    float4 w4 = wr[j];
    int xo = dg*36 + 4*j;
#pragma unroll
    for (int bbi = 0; bbi < 8; ++bbi) {
      float4 x4 = *(const float4*)&X2[bbi*288 + xo];
      acc[bbi] = fmaf(w4.x,x4.x, fmaf(w4.y,x4.y, fmaf(w4.z,x4.z, fmaf(w4.w,x4.w, acc[bbi]))));
    }
  }
#pragma unroll
  for (int bbi = 0; bbi < 8; ++bbi) part[(ol*8+bbi)*9 + dg] = acc[bbi];
  __syncthreads();
  int o = t >> 3, bbo = t & 7;
  const float* pp = &part[(o*8+bbo)*9];
  float v = ((pp[0]+pp[1])+(pp[2]+pp[3]))+((pp[4]+pp[5])+(pp[6]+pp[7]));
  emit(o, bbo, v);
}

__global__ __launch_bounds__(256, 1) void mega(P p) {
  __shared__ __align__(16) float smem[10648];   // 42.6 KB union
  const int blk = blockIdx.x;
  const int t = threadIdx.x;
  const int wid = t >> 6, lane = t & 63;
  int* bar = p.bar;
  int bc = 0;

  // ================= PHASE A1: ck/cv, slots init, Pg GEMM =================
  if (blk < 32) {
    int s = blk >> 2, oq = blk & 3;
    float4 bi = ((const float4*)(p.b_in + s*DD))[lane];
    for (int r = 0; r < 16; ++r) {
      int o = oq*64 + wid*16 + r;
      float4 wk4 = ((const float4*)(p.Wk + ((size_t)s*DD + o)*DD))[lane];
      float4 wv4 = ((const float4*)(p.Wv + ((size_t)s*DD + o)*DD))[lane];
      float pk = wredsum(bi.x*wk4.x + bi.y*wk4.y + bi.z*wk4.z + bi.w*wk4.w);
      float pv = wredsum(bi.x*wv4.x + bi.y*wv4.y + bi.z*wv4.z + bi.w*wv4.w);
      if (lane == 0) {
        p.ck[s*DD+o] = pk + p.bk[s*DD+o];
        p.cv[s*DD+o] = pv + p.bv[s*DD+o];
      }
    }
  } else if (blk < 96) {
    int idx = (blk-32)*256 + t;       // < B*S*D
    int sd = idx & 2047;
    p.slots[idx] = p.smu[sd] + __expf(p.slsig[sd]) * p.noise[idx];
  }
  {
    float* Ak = smem;             // 32*33
    float* Aq = smem + 1056;      // 32*33
    for (int tile2 = blk; tile2 < 512; tile2 += 256) {
      int s = tile2 >> 6, tile = tile2 & 63;
      int td = tile >> 3, te = tile & 7;
      int dli = t >> 5, el = t & 31;
      float acc[4] = {0.f,0.f,0.f,0.f};
      for (int o0 = 0; o0 < DD; o0 += 32) {
        __syncthreads();
        for (int i = t; i < 1024; i += 256) {
          int o = i >> 5, c = i & 31;
          Ak[o*33+c] = p.Wk[((size_t)s*DD + o0+o)*DD + td*32 + c];
          Aq[o*33+c] = p.Wq[((size_t)s*DD + o0+o)*DD + te*32 + c];
        }
        __syncthreads();
#pragma unroll 8
        for (int o = 0; o < 32; ++o) {
          float aq = Aq[o*33+el];
#pragma unroll
          for (int j = 0; j < 4; ++j)
            acc[j] += Ak[o*33 + dli*4 + j] * aq;
        }
      }
#pragma unroll
      for (int j = 0; j < 4; ++j) {
        int d = td*32 + dli*4 + j;
        p.Pg[((size_t)s*DD + d)*DD + te*32 + el] = p.g_in[s*DD + d] * acc[j];
      }
    }
  }
  gbar(bar, ++bc * GRID);

  // ================= PHASE A2: vq, qcon, c0 (needs ck) =================
  if (blk < 16) {
    float* cvec  = smem;          // 256
    float* part2 = smem + 256;    // 8*264
    int s = blk >> 1, which = blk & 1;
    const float* W = which ? p.Wk : p.Wq;
    const float* vec = which ? p.bq : p.ck;
    cvec[t] = vec[s*DD + t];
    __syncthreads();
    int og = t >> 5, eg = t & 31;
    float acc[8] = {0.f,0.f,0.f,0.f,0.f,0.f,0.f,0.f};
    for (int oi = 0; oi < 32; ++oi) {
      int o = og*32 + oi;
      float cv2 = cvec[o];
      const float4* wrow = (const float4*)(W + ((size_t)s*DD + o)*DD + eg*8);
      float4 w0 = wrow[0], w1 = wrow[1];
      acc[0] += w0.x*cv2; acc[1] += w0.y*cv2; acc[2] += w0.z*cv2; acc[3] += w0.w*cv2;
      acc[4] += w1.x*cv2; acc[5] += w1.y*cv2; acc[6] += w1.z*cv2; acc[7] += w1.w*cv2;
    }
#pragma unroll
    for (int j = 0; j < 8; ++j) part2[og*264 + eg*8 + j] = acc[j];
    __syncthreads();
    float v = 0.f;
#pragma unroll
    for (int og2 = 0; og2 < 8; ++og2) v += part2[og2*264 + t];
    if (which) p.qcon[s*DD + t] = v * p.g_in[s*DD + t];
    else       p.vq[s*DD + t]   = v;
    if (which == 0 && t < 64) {
      float4 b4 = ((const float4*)(p.bq + s*DD))[t];
      float4 c4 = ((const float4*)(p.ck + s*DD))[t];
      float vv = wredsum(b4.x*c4.x + b4.y*c4.y + b4.z*c4.z + b4.w*c4.w);
      if (t == 0) p.c0[s] = vv;
    }
  }
  gbar(bar, ++bc * GRID);

  // ================= ITERATIONS =================
  for (int it = 0; it < 3; ++it) {
    const int last = (it == 2);
    float* X2   = smem;           // 8*288
    float* part = smem + 2304;    // 32*8*9

    // ---- B1: q-chain (blocks 0..63)  ||  gh = Whh.slots + bhh (blocks 64..255) ----
    if (blk < 64) {
      int s = blk >> 3, rc = blk & 7;
      float4 g4 = ((const float4*)(p.g_ns + s*DD))[lane];
      float4 p4 = ((const float4*)(p.b_ns + s*DD))[lane];
#pragma unroll
      for (int half = 0; half < 2; ++half) {
        int bb2 = wid + half*4;
        const float4* src = (const float4*)(p.slots + (size_t)(bb2*8+s)*DD);
        float4 x = src[lane];
        float sv = wredsum(x.x+x.y+x.z+x.w);
        float sq = wredsum(x.x*x.x + x.y*x.y + x.z*x.z + x.w*x.w);
        float mu = sv*(1.f/DD), var = sq*(1.f/DD)-mu*mu, rs = rsqrtf(var+F_LNEPS);
        int base = bb2*288 + (lane>>3)*36 + (lane&7)*4;
        X2[base]   = (x.x-mu)*rs*g4.x + p4.x;
        X2[base+1] = (x.y-mu)*rs*g4.y + p4.y;
        X2[base+2] = (x.z-mu)*rs*g4.z + p4.z;
        X2[base+3] = (x.w-mu)*rs*g4.w + p4.w;
      }
      if (rc == 0) {
        for (int i = t; i < 2048; i += 256) {
          int bb2 = i >> 8, dd = i & 255;
          p.axun[(size_t)(bb2*8+s)*DD + dd] = 0.f;
        }
        if (t < 8) p.rsum[t*8+s] = 0.f;
      }
      __syncthreads();
      if (rc == 0) {           // qc for all 8 b's of this slot
        int b = t >> 5, l32 = t & 31;
        float v = 0.f;
#pragma unroll
        for (int j = 0; j < 8; ++j)
          v += X2[b*288 + j*36 + l32] * p.vq[s*DD + j*32 + l32];
#pragma unroll
        for (int m = 16; m > 0; m >>= 1) v += __shfl_xor(v, m, 64);
        if (l32 == 0) p.qc[b*8+s] = v + p.c0[s];
      }
      gemv32(p.Pg + ((size_t)s*DD + rc*32)*DD, X2, part, [&](int o,int bb2,float v){
        p.qg[(size_t)(bb2*8+s)*DD + rc*32 + o] = v + p.qcon[s*DD + rc*32 + o];
      });
    } else {
      int idx = blk - 64;            // 0..191 = s*24 + jt
      int s = idx / 24, jt = idx % 24;
      for (int i = t; i < 2048; i += 256) {
        int bb2 = i >> 8, dd = i & 255;
        X2[x2i(bb2,dd)] = p.slots[(size_t)(bb2*8+s)*DD + dd];
      }
      int ob = jt*32;
      gemv32(p.Whh + ((size_t)s*768 + ob)*DD, X2, part, [&](int o,int bb2,float v){
        p.ghb[(size_t)(bb2*8+s)*768 + ob + o] = v + p.bhh[s*768 + ob + o];
      });
    }
    gbar(bar, ++bc * GRID);

    // ---- B2: LN(inputs) + dots + softmax(slots) + rowsum + ax (all 256 blocks) ----
    {
      float* qgl = smem;            // 2048
      float* xt  = smem + 2048;     // 32*260
      float* dl  = smem + 10368;    // 8*33
      float* qcl = smem + 10632;    // 8
      float* rsl = smem + 10640;    // 8
      int b = blk >> 5;
      int chunk = blk & 31;
      for (int i = t; i < SS*DD; i += 256) qgl[i] = p.qg[(size_t)b*SS*DD + i];
      if (t < 8) { qcl[t] = p.qc[b*8+t]; rsl[t] = 0.f; }
      int si = t >> 5, ni = t & 31;
      float axa[8] = {0.f,0.f,0.f,0.f,0.f,0.f,0.f,0.f};
      for (int tile = 0; tile < 2; ++tile) {
        int n0 = (chunk*2 + tile) * 32;
        __syncthreads();
#pragma unroll
        for (int rr = 0; rr < 8; ++rr) {
          int r = wid*8 + rr;
          const float4* src = (const float4*)(p.inputs + ((size_t)b*NT + n0 + r)*DD);
          float4 x = src[lane];
          float sv = wredsum(x.x + x.y + x.z + x.w);
          float sq = wredsum(x.x*x.x + x.y*x.y + x.z*x.z + x.w*x.w);
          float mu = sv*(1.f/DD), var = sq*(1.f/DD)-mu*mu, rs = rsqrtf(var+F_LNEPS);
          float4 o;
          o.x=(x.x-mu)*rs; o.y=(x.y-mu)*rs; o.z=(x.z-mu)*rs; o.w=(x.w-mu)*rs;
          *(float4*)&xt[r*260 + lane*4] = o;
        }
        __syncthreads();
        float acc = 0.f;
        {
          const float4* xr = (const float4*)&xt[ni*260];
          const float4* qr = (const float4*)&qgl[si*DD];
#pragma unroll 8
          for (int j = 0; j < 64; ++j) {
            float4 a4 = xr[j]; float4 b4 = qr[j];
            acc += a4.x*b4.x + a4.y*b4.y + a4.z*b4.z + a4.w*b4.w;
          }
        }
        float dot = (acc + qcl[si]) * F_SCALE;
        dl[si*33+ni] = dot;
        __syncthreads();
        float m = dl[ni];
#pragma unroll
        for (int ss2 = 1; ss2 < 8; ++ss2) m = fmaxf(m, dl[ss2*33+ni]);
        float den = 0.f;
#pragma unroll
        for (int ss2 = 0; ss2 < 8; ++ss2) den += __expf(dl[ss2*33+ni] - m);
        float a = __expf(dot - m) / den + F_EPS;
        __syncthreads();
        dl[si*33+ni] = a;
        float rv = a;
#pragma unroll
        for (int mm = 16; mm > 0; mm >>= 1) rv += __shfl_xor(rv, mm, 64);
        if (ni == 0) rsl[si] += rv;
        if (last) p.out_attn[(size_t)(b*8+si)*NT + n0 + ni] = a;
        __syncthreads();
#pragma unroll
        for (int n = 0; n < 32; ++n) {
          float x = xt[n*260 + t];
#pragma unroll
          for (int ss2 = 0; ss2 < 8; ++ss2) axa[ss2] += dl[ss2*33+n] * x;
        }
      }
#pragma unroll
      for (int ss2 = 0; ss2 < 8; ++ss2)
        atomicAdd(&p.axun[(size_t)(b*8+ss2)*DD + t], axa[ss2]);
      __syncthreads();
      if (t < 8) atomicAdd(&p.rsum[b*8+t], rsl[t]);
    }
    gbar(bar, ++bc * GRID);

    // ---- B3: upd = Wv.(axun*g_in/rsum) + cv (blocks 0..63) ----
    if (blk < 64) {
      int s = blk >> 3, rc = blk & 7;
      for (int i = t; i < 2048; i += 256) {
        int bb2 = i >> 8, dd = i & 255;
        X2[x2i(bb2,dd)] = p.axun[(size_t)(bb2*8+s)*DD + dd] / p.rsum[bb2*8+s] * p.g_in[s*DD+dd];
      }
      int ob = rc*32;
      gemv32(p.Wv + ((size_t)s*DD + ob)*DD, X2, part, [&](int o,int bb2,float v){
        p.upd[(size_t)(bb2*8+s)*DD + ob + o] = v + p.cv[s*DD + ob + o];
      });
    }
    gbar(bar, ++bc * GRID);

    // ---- B4: gi = Wih.upd ; GRU elementwise -> smid (blocks 0..63) ----
    if (blk < 64) {
      int s = blk >> 3, jc = blk & 7;
      for (int i = t; i < 2048; i += 256) {
        int bb2 = i >> 8, dd = i & 255;
        X2[x2i(bb2,dd)] = p.upd[(size_t)(bb2*8+s)*DD + dd];
      }
      int jb = jc*32;
      float gir = 0.f, giz = 0.f, gin = 0.f;
      gemv32(p.Wih + ((size_t)s*768 + jb)*DD, X2, part,
             [&](int o,int bb2,float v){ (void)o; (void)bb2; gir = v + p.bih[s*768 + jb + (threadIdx.x>>3)]; });
      gemv32(p.Wih + ((size_t)s*768 + 256 + jb)*DD, X2, part,
             [&](int o,int bb2,float v){ (void)o; (void)bb2; giz = v + p.bih[s*768 + 256 + jb + (threadIdx.x>>3)]; });
      gemv32(p.Wih + ((size_t)s*768 + 512 + jb)*DD, X2, part,
             [&](int o,int bb2,float v){ (void)o; (void)bb2; gin = v + p.bih[s*768 + 512 + jb + (threadIdx.x>>3)]; });
      int j = t >> 3, bb2 = t & 7;
      size_t gb = (size_t)(bb2*8+s)*768 + jb + j;
      float r = sigm(gir + p.ghb[gb]);
      float z = sigm(giz + p.ghb[gb+256]);
      float nn2 = tanhfast(gin + r*p.ghb[gb+512]);
      size_t si2 = (size_t)(bb2*8+s)*DD + jb + j;
      float sp = p.slots[si2];
      p.smid[si2] = (1.f - z)*nn2 + z*sp;
    }
    gbar(bar, ++bc * GRID);

    // ---- B5: pre = LN(smid)*g_pf+b_pf ; h1 = relu(W1.pre + b1) (blocks 0..63) ----
    if (blk < 64) {
      int s = blk >> 3, rc = blk & 7;
#pragma unroll
      for (int half = 0; half < 2; ++half) {
        int bb2 = wid + half*4;
        const float4* src = (const float4*)(p.smid + (size_t)(bb2*8+s)*DD);
        float4 x = src[lane];
        float sv = wredsum(x.x+x.y+x.z+x.w);
        float sq = wredsum(x.x*x.x + x.y*x.y + x.z*x.z + x.w*x.w);
        float mu = sv*(1.f/DD), var = sq*(1.f/DD)-mu*mu, rs = rsqrtf(var+F_LNEPS);
        float4 g4 = ((const float4*)(p.g_pf + s*DD))[lane];
        float4 p4 = ((const float4*)(p.b_pf + s*DD))[lane];
        int base = bb2*288 + (lane>>3)*36 + (lane&7)*4;
        X2[base]   = (x.x-mu)*rs*g4.x + p4.x;
        X2[base+1] = (x.y-mu)*rs*g4.y + p4.y;
        X2[base+2] = (x.z-mu)*rs*g4.z + p4.z;
        X2[base+3] = (x.w-mu)*rs*g4.w + p4.w;
      }
      gemv32(p.W1 + ((size_t)s*HH + rc*32)*DD, X2, part, [&](int o,int bb2,float v){
        float rr = v + p.b1[s*HH + rc*32 + o];
        p.h1b[(size_t)(bb2*8+s)*HH + rc*32 + o] = fmaxf(rr, 0.f);
      });
    }
    gbar(bar, ++bc * GRID);

    // ---- B6: slots = smid + W2.h1 + b2  (blocks 0..63; write out on last) ----
    if (blk < 64) {
      int s = blk >> 3, rc = blk & 7;
      for (int i = t; i < 2048; i += 256) {
        int bb2 = i >> 8, dd = i & 255;
        X2[x2i(bb2,dd)] = p.h1b[(size_t)(bb2*8+s)*HH + dd];
      }
      gemv32(p.W2 + ((size_t)s*DD + rc*32)*HH, X2, part, [&](int o,int bb2,float v){
        int d = rc*32 + o;
        size_t idx = (size_t)(bb2*8+s)*DD + d;
        float rr = v + p.b2[s*DD + d] + p.smid[idx];
        p.slots[idx] = rr;
        if (last) p.out_slots[idx] = rr;
      });
    }
    if (it != 2) gbar(bar, ++bc * GRID);
  }
}

extern "C" void kernel_launch(void* const* d_in, const int* in_sizes, int n_in,
                              void* d_out, int out_size, void* d_ws, size_t ws_size,
                              hipStream_t stream) {
  (void)in_sizes; (void)n_in; (void)out_size; (void)ws_size;
  float* ws = (float*)d_ws;
  P p;
  p.inputs = (const float*)d_in[0];
  p.noise  = (const float*)d_in[1];
  p.smu    = (const float*)d_in[2];
  p.slsig  = (const float*)d_in[3];
  p.g_in   = (const float*)d_in[4];
  p.b_in   = (const float*)d_in[5];
  p.g_ns   = (const float*)d_in[6];
  p.b_ns   = (const float*)d_in[7];
  p.g_pf   = (const float*)d_in[8];
  p.b_pf   = (const float*)d_in[9];
  p.Wq  = (const float*)d_in[10];
  p.bq  = (const float*)d_in[11];
  p.Wk  = (const float*)d_in[12];
  p.bk  = (const float*)d_in[13];
  p.Wv  = (const float*)d_in[14];
  p.bv  = (const float*)d_in[15];
  p.Wih = (const float*)d_in[16];
  p.bih = (const float*)d_in[17];
  p.Whh = (const float*)d_in[18];
  p.bhh = (const float*)d_in[19];
  p.W1  = (const float*)d_in[20];
  p.b1  = (const float*)d_in[21];
  p.W2  = (const float*)d_in[22];
  p.b2  = (const float*)d_in[23];

  p.slots = ws;                         ws += BB*SS*DD;     // 16384
  p.smid  = ws;                         ws += BB*SS*DD;     // 16384
  p.ck    = ws;                         ws += SS*DD;        // 2048
  p.cv    = ws;                         ws += SS*DD;        // 2048
  p.qg    = ws;                         ws += BB*SS*DD;     // 16384
  p.qc    = ws;                         ws += BB*SS;        // 64
  p.rsum  = ws;                         ws += BB*SS;        // 64
  p.axun  = ws;                         ws += BB*SS*DD;     // 16384
  p.upd   = ws;                         ws += BB*SS*DD;     // 16384
  p.ghb   = ws;                         ws += BB*SS*768;    // 49152
  p.h1b   = ws;                         ws += BB*SS*HH;     // 16384
  p.vq    = ws;                         ws += SS*DD;        // 2048
  p.qcon  = ws;                         ws += SS*DD;        // 2048
  p.c0    = ws;                         ws += 64;           // 8 (+pad)
  p.Pg    = ws;                         ws += SS*DD*DD;     // 524288 (2 MB)
  p.bar   = (int*)ws;                                       // barrier counter

  p.out_slots = (float*)d_out;
  p.out_attn  = p.out_slots + BB*SS*DD;

  hipMemsetAsync((void*)p.bar, 0, 64, stream);
  mega<<<dim3(GRID), dim3(256), 0, stream>>>(p);
}

// Round 6
// 399.119 us; speedup vs baseline: 1.3245x; 1.3245x over previous
//
#include <hip/hip_runtime.h>

// Slot Attention fwd, B=8 N=2048 D=256 S=8 H=256 ITERS=3.  All f32.
// Single persistent kernel (plain launch); phases separated by a software
// grid barrier (arrive-array + broadcast-go; no RMW contention).
//   Pg[s] = diag(g_in[s]) * Wk[s]^T Wq[s]   (iteration-invariant, phase A1)
//   qg[b,s] = Pg[s]*sn[b,s] + qcon[s],  qc[b,s] = sn.vq[s] + c0[s]
//   dots[b,s,n] = SCALE*( xn[b,n,:].qg[b,s,:] + qc[b,s] )
//   updates[b,s,o] = (sum_d axun*g_in*Wv)/rowsum + cv[s,o]
// xn = LN(inputs) recomputed on the fly in the dots phase (never stored).

#define BB 8
#define NT 2048
#define DD 256
#define SS 8
#define HH 256
#define GRID 256

static constexpr float F_EPS   = 1e-8f;
static constexpr float F_LNEPS = 1e-5f;
static constexpr float F_SCALE = 0.0625f;   // 256^-0.5

__device__ __forceinline__ float wredsum(float v) {
#pragma unroll
  for (int m = 32; m > 0; m >>= 1) v += __shfl_xor(v, m, 64);
  return v;
}
__device__ __forceinline__ float sigm(float x) { return 1.f / (1.f + __expf(-x)); }
__device__ __forceinline__ float tanhfast(float x) {
  float ax = fabsf(x);
  float e = __expf(2.f * ax);
  float t2 = 1.f - 2.f / (e + 1.f);
  return x < 0.f ? -t2 : t2;
}
// X2 LDS layout: (b,d) -> b*288 + (d>>5)*36 + (d&31)   (bank-conflict-free)
__device__ __forceinline__ int x2i(int bb, int dd) { return bb*288 + (dd>>5)*36 + (dd&31); }

// Contention-free grid barrier. arrive[b*32] (128B-strided slots), one go word.
// Flags zeroed by hipMemsetAsync before each launch; ph = 1,2,3,...
__device__ __forceinline__ void gbar(int* arrive, int* go, int ph) {
  __syncthreads();
  if (threadIdx.x == 0) __threadfence();   // release: L2 writeback (all block writes are in L2)
  __syncthreads();
  if (blockIdx.x == 0) {
    if (threadIdx.x > 0) {                 // poll blocks 1..255, each thread its own line
      while (__hip_atomic_load(&arrive[threadIdx.x * 32], __ATOMIC_RELAXED,
                               __HIP_MEMORY_SCOPE_AGENT) < ph)
        __builtin_amdgcn_s_sleep(1);
    }
    __syncthreads();
    if (threadIdx.x == 0)
      __hip_atomic_store(go, ph, __ATOMIC_RELAXED, __HIP_MEMORY_SCOPE_AGENT);
  } else {
    if (threadIdx.x == 0) {
      __hip_atomic_store(&arrive[blockIdx.x * 32], ph, __ATOMIC_RELAXED,
                         __HIP_MEMORY_SCOPE_AGENT);
      while (__hip_atomic_load(go, __ATOMIC_RELAXED, __HIP_MEMORY_SCOPE_AGENT) < ph)
        __builtin_amdgcn_s_sleep(2);
    }
  }
  __syncthreads();
  if (threadIdx.x == 0) __threadfence();   // acquire: L2 invalidate
  __syncthreads();
}

struct P {
  const float *inputs,*noise,*smu,*slsig,*g_in,*b_in,*g_ns,*b_ns,*g_pf,*b_pf;
  const float *Wq,*bq,*Wk,*bk,*Wv,*bv,*Wih,*bih,*Whh,*bhh,*W1,*b1,*W2,*b2;
  float *slots,*smid,*ck,*cv,*qg,*qc,*rsum,*axun,*upd,*ghb,*h1b,*vq,*qcon,*c0,*Pg;
  float *out_slots,*out_attn;
  int *arrive,*go;
};

template <typename F>
__device__ __forceinline__ void gemv32(const float* __restrict__ Wrow0,
                                       const float* __restrict__ X2,
                                       float* __restrict__ part, F emit) {
  int t = threadIdx.x;
  int ol = t >> 3, dg = t & 7;
  const float4* wr = (const float4*)(Wrow0 + (size_t)ol*256 + (size_t)dg*32);
  __syncthreads();                 // X2 staged / part free
  float acc[8] = {0.f,0.f,0.f,0.f,0.f,0.f,0.f,0.f};
#pragma unroll
  for (int j = 0; j < 8; ++j) {
    float4 w4 = wr[j];
    int xo = dg*36 + 4*j;
#pragma unroll
    for (int bbi = 0; bbi < 8; ++bbi) {
      float4 x4 = *(const float4*)&X2[bbi*288 + xo];
      acc[bbi] = fmaf(w4.x,x4.x, fmaf(w4.y,x4.y, fmaf(w4.z,x4.z, fmaf(w4.w,x4.w, acc[bbi]))));
    }
  }
#pragma unroll
  for (int bbi = 0; bbi < 8; ++bbi) part[(ol*8+bbi)*9 + dg] = acc[bbi];
  __syncthreads();
  int o = t >> 3, bbo = t & 7;
  const float* pp = &part[(o*8+bbo)*9];
  float v = ((pp[0]+pp[1])+(pp[2]+pp[3]))+((pp[4]+pp[5])+(pp[6]+pp[7]));
  emit(o, bbo, v);
}

__global__ __launch_bounds__(256, 1) void mega(P p) {
  __shared__ __align__(16) float smem[10648];   // 42.6 KB union
  const int blk = blockIdx.x;
  const int t = threadIdx.x;
  const int wid = t >> 6, lane = t & 63;
  int* arrive = p.arrive;
  int* go = p.go;
  int bc = 0;

  // ================= PHASE A1: ck/cv, slots init, Pg GEMM =================
  if (blk < 32) {
    int s = blk >> 2, oq = blk & 3;
    float4 bi = ((const float4*)(p.b_in + s*DD))[lane];
    for (int r = 0; r < 16; ++r) {
      int o = oq*64 + wid*16 + r;
      float4 wk4 = ((const float4*)(p.Wk + ((size_t)s*DD + o)*DD))[lane];
      float4 wv4 = ((const float4*)(p.Wv + ((size_t)s*DD + o)*DD))[lane];
      float pk = wredsum(bi.x*wk4.x + bi.y*wk4.y + bi.z*wk4.z + bi.w*wk4.w);
      float pv = wredsum(bi.x*wv4.x + bi.y*wv4.y + bi.z*wv4.z + bi.w*wv4.w);
      if (lane == 0) {
        p.ck[s*DD+o] = pk + p.bk[s*DD+o];
        p.cv[s*DD+o] = pv + p.bv[s*DD+o];
      }
    }
  } else if (blk < 96) {
    int idx = (blk-32)*256 + t;       // < B*S*D
    int sd = idx & 2047;
    p.slots[idx] = p.smu[sd] + __expf(p.slsig[sd]) * p.noise[idx];
  }
  {
    float* Ak = smem;             // 32*33
    float* Aq = smem + 1056;      // 32*33
    for (int tile2 = blk; tile2 < 512; tile2 += 256) {
      int s = tile2 >> 6, tile = tile2 & 63;
      int td = tile >> 3, te = tile & 7;
      int dli = t >> 5, el = t & 31;
      float acc[4] = {0.f,0.f,0.f,0.f};
      for (int o0 = 0; o0 < DD; o0 += 32) {
        __syncthreads();
        for (int i = t; i < 1024; i += 256) {
          int o = i >> 5, c = i & 31;
          Ak[o*33+c] = p.Wk[((size_t)s*DD + o0+o)*DD + td*32 + c];
          Aq[o*33+c] = p.Wq[((size_t)s*DD + o0+o)*DD + te*32 + c];
        }
        __syncthreads();
#pragma unroll 8
        for (int o = 0; o < 32; ++o) {
          float aq = Aq[o*33+el];
#pragma unroll
          for (int j = 0; j < 4; ++j)
            acc[j] += Ak[o*33 + dli*4 + j] * aq;
        }
      }
#pragma unroll
      for (int j = 0; j < 4; ++j) {
        int d = td*32 + dli*4 + j;
        p.Pg[((size_t)s*DD + d)*DD + te*32 + el] = p.g_in[s*DD + d] * acc[j];
      }
    }
  }
  gbar(arrive, go, ++bc);

  // ================= PHASE A2: vq, qcon, c0 (needs ck) =================
  if (blk < 16) {
    float* cvec  = smem;          // 256
    float* part2 = smem + 256;    // 8*264
    int s = blk >> 1, which = blk & 1;
    const float* W = which ? p.Wk : p.Wq;
    const float* vec = which ? p.bq : p.ck;
    cvec[t] = vec[s*DD + t];
    __syncthreads();
    int og = t >> 5, eg = t & 31;
    float acc[8] = {0.f,0.f,0.f,0.f,0.f,0.f,0.f,0.f};
    for (int oi = 0; oi < 32; ++oi) {
      int o = og*32 + oi;
      float cv2 = cvec[o];
      const float4* wrow = (const float4*)(W + ((size_t)s*DD + o)*DD + eg*8);
      float4 w0 = wrow[0], w1 = wrow[1];
      acc[0] += w0.x*cv2; acc[1] += w0.y*cv2; acc[2] += w0.z*cv2; acc[3] += w0.w*cv2;
      acc[4] += w1.x*cv2; acc[5] += w1.y*cv2; acc[6] += w1.z*cv2; acc[7] += w1.w*cv2;
    }
#pragma unroll
    for (int j = 0; j < 8; ++j) part2[og*264 + eg*8 + j] = acc[j];
    __syncthreads();
    float v = 0.f;
#pragma unroll
    for (int og2 = 0; og2 < 8; ++og2) v += part2[og2*264 + t];
    if (which) p.qcon[s*DD + t] = v * p.g_in[s*DD + t];
    else       p.vq[s*DD + t]   = v;
    if (which == 0 && t < 64) {
      float4 b4 = ((const float4*)(p.bq + s*DD))[t];
      float4 c4 = ((const float4*)(p.ck + s*DD))[t];
      float vv = wredsum(b4.x*c4.x + b4.y*c4.y + b4.z*c4.z + b4.w*c4.w);
      if (t == 0) p.c0[s] = vv;
    }
  }
  gbar(arrive, go, ++bc);

  // ================= ITERATIONS =================
  for (int it = 0; it < 3; ++it) {
    const int last = (it == 2);
    float* X2   = smem;           // 8*288
    float* part = smem + 2304;    // 32*8*9

    // ---- B1: q-chain (blocks 0..63)  ||  gh = Whh.slots + bhh (blocks 64..255) ----
    if (blk < 64) {
      int s = blk >> 3, rc = blk & 7;
      float4 g4 = ((const float4*)(p.g_ns + s*DD))[lane];
      float4 p4 = ((const float4*)(p.b_ns + s*DD))[lane];
#pragma unroll
      for (int half = 0; half < 2; ++half) {
        int bb2 = wid + half*4;
        const float4* src = (const float4*)(p.slots + (size_t)(bb2*8+s)*DD);
        float4 x = src[lane];
        float sv = wredsum(x.x+x.y+x.z+x.w);
        float sq = wredsum(x.x*x.x + x.y*x.y + x.z*x.z + x.w*x.w);
        float mu = sv*(1.f/DD), var = sq*(1.f/DD)-mu*mu, rs = rsqrtf(var+F_LNEPS);
        int base = bb2*288 + (lane>>3)*36 + (lane&7)*4;
        X2[base]   = (x.x-mu)*rs*g4.x + p4.x;
        X2[base+1] = (x.y-mu)*rs*g4.y + p4.y;
        X2[base+2] = (x.z-mu)*rs*g4.z + p4.z;
        X2[base+3] = (x.w-mu)*rs*g4.w + p4.w;
      }
      if (rc == 0) {
        for (int i = t; i < 2048; i += 256) {
          int bb2 = i >> 8, dd = i & 255;
          p.axun[(size_t)(bb2*8+s)*DD + dd] = 0.f;
        }
        if (t < 8) p.rsum[t*8+s] = 0.f;
      }
      __syncthreads();
      if (rc == 0) {           // qc for all 8 b's of this slot
        int b = t >> 5, l32 = t & 31;
        float v = 0.f;
#pragma unroll
        for (int j = 0; j < 8; ++j)
          v += X2[b*288 + j*36 + l32] * p.vq[s*DD + j*32 + l32];
#pragma unroll
        for (int m = 16; m > 0; m >>= 1) v += __shfl_xor(v, m, 64);
        if (l32 == 0) p.qc[b*8+s] = v + p.c0[s];
      }
      gemv32(p.Pg + ((size_t)s*DD + rc*32)*DD, X2, part, [&](int o,int bb2,float v){
        p.qg[(size_t)(bb2*8+s)*DD + rc*32 + o] = v + p.qcon[s*DD + rc*32 + o];
      });
    } else {
      int idx = blk - 64;            // 0..191 = s*24 + jt
      int s = idx / 24, jt = idx % 24;
      for (int i = t; i < 2048; i += 256) {
        int bb2 = i >> 8, dd = i & 255;
        X2[x2i(bb2,dd)] = p.slots[(size_t)(bb2*8+s)*DD + dd];
      }
      int ob = jt*32;
      gemv32(p.Whh + ((size_t)s*768 + ob)*DD, X2, part, [&](int o,int bb2,float v){
        p.ghb[(size_t)(bb2*8+s)*768 + ob + o] = v + p.bhh[s*768 + ob + o];
      });
    }
    gbar(arrive, go, ++bc);

    // ---- B2: LN(inputs) + dots + softmax(slots) + rowsum + ax (all 256 blocks) ----
    {
      float* qgl = smem;            // 2048
      float* xt  = smem + 2048;     // 32*260
      float* dl  = smem + 10368;    // 8*33
      float* qcl = smem + 10632;    // 8
      float* rsl = smem + 10640;    // 8
      int b = blk >> 5;
      int chunk = blk & 31;
      for (int i = t; i < SS*DD; i += 256) qgl[i] = p.qg[(size_t)b*SS*DD + i];
      if (t < 8) { qcl[t] = p.qc[b*8+t]; rsl[t] = 0.f; }
      int si = t >> 5, ni = t & 31;
      float axa[8] = {0.f,0.f,0.f,0.f,0.f,0.f,0.f,0.f};
      for (int tile = 0; tile < 2; ++tile) {
        int n0 = (chunk*2 + tile) * 32;
        __syncthreads();
#pragma unroll
        for (int rr = 0; rr < 8; ++rr) {
          int r = wid*8 + rr;
          const float4* src = (const float4*)(p.inputs + ((size_t)b*NT + n0 + r)*DD);
          float4 x = src[lane];
          float sv = wredsum(x.x + x.y + x.z + x.w);
          float sq = wredsum(x.x*x.x + x.y*x.y + x.z*x.z + x.w*x.w);
          float mu = sv*(1.f/DD), var = sq*(1.f/DD)-mu*mu, rs = rsqrtf(var+F_LNEPS);
          float4 o;
          o.x=(x.x-mu)*rs; o.y=(x.y-mu)*rs; o.z=(x.z-mu)*rs; o.w=(x.w-mu)*rs;
          *(float4*)&xt[r*260 + lane*4] = o;
        }
        __syncthreads();
        float acc = 0.f;
        {
          const float4* xr = (const float4*)&xt[ni*260];
          const float4* qr = (const float4*)&qgl[si*DD];
#pragma unroll 8
          for (int j = 0; j < 64; ++j) {
            float4 a4 = xr[j]; float4 b4 = qr[j];
            acc += a4.x*b4.x + a4.y*b4.y + a4.z*b4.z + a4.w*b4.w;
          }
        }
        float dot = (acc + qcl[si]) * F_SCALE;
        dl[si*33+ni] = dot;
        __syncthreads();
        float m = dl[ni];
#pragma unroll
        for (int ss2 = 1; ss2 < 8; ++ss2) m = fmaxf(m, dl[ss2*33+ni]);
        float den = 0.f;
#pragma unroll
        for (int ss2 = 0; ss2 < 8; ++ss2) den += __expf(dl[ss2*33+ni] - m);
        float a = __expf(dot - m) / den + F_EPS;
        __syncthreads();
        dl[si*33+ni] = a;
        float rv = a;
#pragma unroll
        for (int mm = 16; mm > 0; mm >>= 1) rv += __shfl_xor(rv, mm, 64);
        if (ni == 0) rsl[si] += rv;
        if (last) p.out_attn[(size_t)(b*8+si)*NT + n0 + ni] = a;
        __syncthreads();
#pragma unroll
        for (int n = 0; n < 32; ++n) {
          float x = xt[n*260 + t];
#pragma unroll
          for (int ss2 = 0; ss2 < 8; ++ss2) axa[ss2] += dl[ss2*33+n] * x;
        }
      }
#pragma unroll
      for (int ss2 = 0; ss2 < 8; ++ss2)
        atomicAdd(&p.axun[(size_t)(b*8+ss2)*DD + t], axa[ss2]);
      __syncthreads();
      if (t < 8) atomicAdd(&p.rsum[b*8+t], rsl[t]);
    }
    gbar(arrive, go, ++bc);

    // ---- B3: upd = Wv.(axun*g_in/rsum) + cv (blocks 0..63) ----
    if (blk < 64) {
      int s = blk >> 3, rc = blk & 7;
      for (int i = t; i < 2048; i += 256) {
        int bb2 = i >> 8, dd = i & 255;
        X2[x2i(bb2,dd)] = p.axun[(size_t)(bb2*8+s)*DD + dd] / p.rsum[bb2*8+s] * p.g_in[s*DD+dd];
      }
      int ob = rc*32;
      gemv32(p.Wv + ((size_t)s*DD + ob)*DD, X2, part, [&](int o,int bb2,float v){
        p.upd[(size_t)(bb2*8+s)*DD + ob + o] = v + p.cv[s*DD + ob + o];
      });
    }
    gbar(arrive, go, ++bc);

    // ---- B4: gi = Wih.upd ; GRU elementwise -> smid (blocks 0..63) ----
    if (blk < 64) {
      int s = blk >> 3, jc = blk & 7;
      for (int i = t; i < 2048; i += 256) {
        int bb2 = i >> 8, dd = i & 255;
        X2[x2i(bb2,dd)] = p.upd[(size_t)(bb2*8+s)*DD + dd];
      }
      int jb = jc*32;
      float gir = 0.f, giz = 0.f, gin = 0.f;
      gemv32(p.Wih + ((size_t)s*768 + jb)*DD, X2, part,
             [&](int o,int bb2,float v){ (void)o; (void)bb2; gir = v + p.bih[s*768 + jb + (threadIdx.x>>3)]; });
      gemv32(p.Wih + ((size_t)s*768 + 256 + jb)*DD, X2, part,
             [&](int o,int bb2,float v){ (void)o; (void)bb2; giz = v + p.bih[s*768 + 256 + jb + (threadIdx.x>>3)]; });
      gemv32(p.Wih + ((size_t)s*768 + 512 + jb)*DD, X2, part,
             [&](int o,int bb2,float v){ (void)o; (void)bb2; gin = v + p.bih[s*768 + 512 + jb + (threadIdx.x>>3)]; });
      int j = t >> 3, bb2 = t & 7;
      size_t gb = (size_t)(bb2*8+s)*768 + jb + j;
      float r = sigm(gir + p.ghb[gb]);
      float z = sigm(giz + p.ghb[gb+256]);
      float nn2 = tanhfast(gin + r*p.ghb[gb+512]);
      size_t si2 = (size_t)(bb2*8+s)*DD + jb + j;
      float sp = p.slots[si2];
      p.smid[si2] = (1.f - z)*nn2 + z*sp;
    }
    gbar(arrive, go, ++bc);

    // ---- B5: pre = LN(smid)*g_pf+b_pf ; h1 = relu(W1.pre + b1) (blocks 0..63) ----
    if (blk < 64) {
      int s = blk >> 3, rc = blk & 7;
#pragma unroll
      for (int half = 0; half < 2; ++half) {
        int bb2 = wid + half*4;
        const float4* src = (const float4*)(p.smid + (size_t)(bb2*8+s)*DD);
        float4 x = src[lane];
        float sv = wredsum(x.x+x.y+x.z+x.w);
        float sq = wredsum(x.x*x.x + x.y*x.y + x.z*x.z + x.w*x.w);
        float mu = sv*(1.f/DD), var = sq*(1.f/DD)-mu*mu, rs = rsqrtf(var+F_LNEPS);
        float4 g4 = ((const float4*)(p.g_pf + s*DD))[lane];
        float4 p4 = ((const float4*)(p.b_pf + s*DD))[lane];
        int base = bb2*288 + (lane>>3)*36 + (lane&7)*4;
        X2[base]   = (x.x-mu)*rs*g4.x + p4.x;
        X2[base+1] = (x.y-mu)*rs*g4.y + p4.y;
        X2[base+2] = (x.z-mu)*rs*g4.z + p4.z;
        X2[base+3] = (x.w-mu)*rs*g4.w + p4.w;
      }
      gemv32(p.W1 + ((size_t)s*HH + rc*32)*DD, X2, part, [&](int o,int bb2,float v){
        float rr = v + p.b1[s*HH + rc*32 + o];
        p.h1b[(size_t)(bb2*8+s)*HH + rc*32 + o] = fmaxf(rr, 0.f);
      });
    }
    gbar(arrive, go, ++bc);

    // ---- B6: slots = smid + W2.h1 + b2  (blocks 0..63; write out on last) ----
    if (blk < 64) {
      int s = blk >> 3, rc = blk & 7;
      for (int i = t; i < 2048; i += 256) {
        int bb2 = i >> 8, dd = i & 255;
        X2[x2i(bb2,dd)] = p.h1b[(size_t)(bb2*8+s)*HH + dd];
      }
      gemv32(p.W2 + ((size_t)s*DD + rc*32)*HH, X2, part, [&](int o,int bb2,float v){
        int d = rc*32 + o;
        size_t idx = (size_t)(bb2*8+s)*DD + d;
        float rr = v + p.b2[s*DD + d] + p.smid[idx];
        p.slots[idx] = rr;
        if (last) p.out_slots[idx] = rr;
      });
    }
    if (it != 2) gbar(arrive, go, ++bc);
  }
}

extern "C" void kernel_launch(void* const* d_in, const int* in_sizes, int n_in,
                              void* d_out, int out_size, void* d_ws, size_t ws_size,
                              hipStream_t stream) {
  (void)in_sizes; (void)n_in; (void)out_size; (void)ws_size;
  float* ws = (float*)d_ws;
  P p;
  p.inputs = (const float*)d_in[0];
  p.noise  = (const float*)d_in[1];
  p.smu    = (const float*)d_in[2];
  p.slsig  = (const float*)d_in[3];
  p.g_in   = (const float*)d_in[4];
  p.b_in   = (const float*)d_in[5];
  p.g_ns   = (const float*)d_in[6];
  p.b_ns   = (const float*)d_in[7];
  p.g_pf   = (const float*)d_in[8];
  p.b_pf   = (const float*)d_in[9];
  p.Wq  = (const float*)d_in[10];
  p.bq  = (const float*)d_in[11];
  p.Wk  = (const float*)d_in[12];
  p.bk  = (const float*)d_in[13];
  p.Wv  = (const float*)d_in[14];
  p.bv  = (const float*)d_in[15];
  p.Wih = (const float*)d_in[16];
  p.bih = (const float*)d_in[17];
  p.Whh = (const float*)d_in[18];
  p.bhh = (const float*)d_in[19];
  p.W1  = (const float*)d_in[20];
  p.b1  = (const float*)d_in[21];
  p.W2  = (const float*)d_in[22];
  p.b2  = (const float*)d_in[23];

  p.slots = ws;                         ws += BB*SS*DD;     // 16384
  p.smid  = ws;                         ws += BB*SS*DD;     // 16384
  p.ck    = ws;                         ws += SS*DD;        // 2048
  p.cv    = ws;                         ws += SS*DD;        // 2048
  p.qg    = ws;                         ws += BB*SS*DD;     // 16384
  p.qc    = ws;                         ws += BB*SS;        // 64
  p.rsum  = ws;                         ws += BB*SS;        // 64
  p.axun  = ws;                         ws += BB*SS*DD;     // 16384
  p.upd   = ws;                         ws += BB*SS*DD;     // 16384
  p.ghb   = ws;                         ws += BB*SS*768;    // 49152
  p.h1b   = ws;                         ws += BB*SS*HH;     // 16384
  p.vq    = ws;                         ws += SS*DD;        // 2048
  p.qcon  = ws;                         ws += SS*DD;        // 2048
  p.c0    = ws;                         ws += 64;           // 8 (+pad)
  p.Pg    = ws;                         ws += SS*DD*DD;     // 524288 (2 MB)
  p.arrive = (int*)ws;                  ws += GRID*32;      // 128B-strided arrive slots
  p.go     = (int*)ws;                  ws += 32;

  p.out_slots = (float*)d_out;
  p.out_attn  = p.out_slots + BB*SS*DD;

  hipMemsetAsync((void*)p.arrive, 0, (GRID*32 + 32) * sizeof(int), stream);
  mega<<<dim3(GRID), dim3(256), 0, stream>>>(p);
}

// Round 7
// 375.782 us; speedup vs baseline: 1.4067x; 1.0621x over previous
//
#include <hip/hip_runtime.h>

// Slot Attention fwd, B=8 N=2048 D=256 S=8 H=256 ITERS=3.  All f32.
// Multi-kernel, 9 launches. k/v never materialized:
//   Pg[s] = diag(g_in[s]) * Wk[s]^T Wq[s]   (iteration-invariant)
//   qg[b,s] = Pg[s]*sn[b,s] + qcon[s],  qc[b,s] = sn.vq[s] + c0[s]
//   dots[b,s,n] = SCALE*( xn[b,n,:].qg[b,s,:] + qc[b,s] )
//   updates[b,s,o] = (sum_d ax*g_in*Wv)/rowsum + cv[s,o]
// xn = LN(inputs) recomputed on the fly in k_dots (never stored).
// Per-iteration tail (upd->GRU->MLP->next q-chain) fused into k_chain:
// one block per (b,s), all intermediates in LDS, no atomics (chunk partials).

#define BB 8
#define NT 2048
#define DD 256
#define SS 8
#define HH 256

static constexpr float F_EPS   = 1e-8f;
static constexpr float F_LNEPS = 1e-5f;
static constexpr float F_SCALE = 0.0625f;   // 256^-0.5

__device__ __forceinline__ float wredsum(float v) {
#pragma unroll
  for (int m = 32; m > 0; m >>= 1) v += __shfl_xor(v, m, 64);
  return v;
}
__device__ __forceinline__ float sigm(float x) { return 1.f / (1.f + __expf(-x)); }
__device__ __forceinline__ float tanhfast(float x) {
  float ax = fabsf(x);
  float e = __expf(2.f * ax);
  float t2 = 1.f - 2.f / (e + 1.f);
  return x < 0.f ? -t2 : t2;
}

// ---- sync-free 32-row GEMV tile: 256 thr = 32 rows x 8 dgroups ----
// xp: padded X, x[d] at xp[(d>>5)*36 + (d&31)].  emit(row, val) on threads t&7==0.
template <typename F>
__device__ __forceinline__ void gemv_tile(const float* __restrict__ Wrow0,
                                          const float* __restrict__ xp, F emit) {
  int t = threadIdx.x;
  int ol = t >> 3, dg = t & 7;
  const float4* wr = (const float4*)(Wrow0 + (size_t)ol*256 + dg*32);
  float acc = 0.f;
#pragma unroll
  for (int j = 0; j < 8; ++j) {
    float4 w4 = wr[j];
    float4 x4 = *(const float4*)&xp[dg*36 + 4*j];
    acc = fmaf(w4.x,x4.x, fmaf(w4.y,x4.y, fmaf(w4.z,x4.z, fmaf(w4.w,x4.w, acc))));
  }
  acc += __shfl_xor(acc, 1, 64);
  acc += __shfl_xor(acc, 2, 64);
  acc += __shfl_xor(acc, 4, 64);
  if ((t & 7) == 0) emit(ol, acc);
}
__device__ __forceinline__ int xpi(int d) { return (d>>5)*36 + (d&31); }

// ---------------- init1: ck/cv and slots ----------------
__global__ __launch_bounds__(256) void k_init(
    const float* __restrict__ Wk, const float* __restrict__ bk,
    const float* __restrict__ Wv, const float* __restrict__ bv,
    const float* __restrict__ b_in, const float* __restrict__ smu,
    const float* __restrict__ slsig, const float* __restrict__ noise,
    float* __restrict__ ck, float* __restrict__ cv, float* __restrict__ slots) {
  int blk = blockIdx.x;
  int t = threadIdx.x;
  if (blk < 32) {
    int s = blk >> 2, oq = blk & 3;
    int wid = t >> 6, lane = t & 63;
    float4 bi = ((const float4*)(b_in + s*DD))[lane];
    for (int r = 0; r < 16; ++r) {
      int o = oq*64 + wid*16 + r;
      float4 wk4 = ((const float4*)(Wk + ((size_t)s*DD + o)*DD))[lane];
      float4 wv4 = ((const float4*)(Wv + ((size_t)s*DD + o)*DD))[lane];
      float pk = wredsum(bi.x*wk4.x + bi.y*wk4.y + bi.z*wk4.z + bi.w*wk4.w);
      float pv = wredsum(bi.x*wv4.x + bi.y*wv4.y + bi.z*wv4.z + bi.w*wv4.w);
      if (lane == 0) {
        ck[s*DD+o] = pk + bk[s*DD+o];
        cv[s*DD+o] = pv + bv[s*DD+o];
      }
    }
  } else {
    int idx = (blk-32)*256 + t;       // < B*S*D
    int sd = idx & 2047;
    slots[idx] = smu[sd] + __expf(slsig[sd]) * noise[idx];
  }
}

// ---------------- init2: Pg = diag(g_in) Wk^T Wq ; vq, qcon, c0 ----------------
__global__ __launch_bounds__(256) void k_init2(
    const float* __restrict__ Wq, const float* __restrict__ Wk,
    const float* __restrict__ bq, const float* __restrict__ ck,
    const float* __restrict__ g_in,
    float* __restrict__ Pg, float* __restrict__ vq,
    float* __restrict__ qcon, float* __restrict__ c0) {
  int blk = blockIdx.x;
  int t = threadIdx.x;
  if (blk < 512) {
    __shared__ float Ak[32*33], Aq[32*33];
    int s = blk >> 6, tile = blk & 63;
    int td = tile >> 3, te = tile & 7;
    int dl = t >> 5, el = t & 31;
    float acc[4] = {0.f,0.f,0.f,0.f};
    for (int o0 = 0; o0 < DD; o0 += 32) {
      __syncthreads();
      for (int i = t; i < 1024; i += 256) {
        int o = i >> 5, c = i & 31;
        Ak[o*33+c] = Wk[((size_t)s*DD + o0+o)*DD + td*32 + c];
        Aq[o*33+c] = Wq[((size_t)s*DD + o0+o)*DD + te*32 + c];
      }
      __syncthreads();
#pragma unroll 8
      for (int o = 0; o < 32; ++o) {
        float aq = Aq[o*33+el];
#pragma unroll
        for (int j = 0; j < 4; ++j)
          acc[j] += Ak[o*33 + dl*4 + j] * aq;
      }
    }
#pragma unroll
    for (int j = 0; j < 4; ++j) {
      int d = td*32 + dl*4 + j;
      Pg[((size_t)s*DD + d)*DD + te*32 + el] = g_in[s*DD + d] * acc[j];
    }
  } else {
    // blocks 512..527: (s, which): which=0 -> vq=Wq^T ck (+c0), which=1 -> qcon=g_in.(Wk^T bq)
    __shared__ float cvec[DD];
    __shared__ float part2[8*264];
    int idx = blk - 512;
    int s = idx >> 1, which = idx & 1;
    const float* W = which ? Wk : Wq;
    const float* vec = which ? bq : ck;
    cvec[t] = vec[s*DD + t];
    __syncthreads();
    int og = t >> 5, eg = t & 31;
    float acc[8] = {0.f,0.f,0.f,0.f,0.f,0.f,0.f,0.f};
    for (int oi = 0; oi < 32; ++oi) {
      int o = og*32 + oi;
      float cv2 = cvec[o];
      const float4* wrow = (const float4*)(W + ((size_t)s*DD + o)*DD + eg*8);
      float4 w0 = wrow[0], w1 = wrow[1];
      acc[0] += w0.x*cv2; acc[1] += w0.y*cv2; acc[2] += w0.z*cv2; acc[3] += w0.w*cv2;
      acc[4] += w1.x*cv2; acc[5] += w1.y*cv2; acc[6] += w1.z*cv2; acc[7] += w1.w*cv2;
    }
#pragma unroll
    for (int j = 0; j < 8; ++j) part2[og*264 + eg*8 + j] = acc[j];
    __syncthreads();
    float v = 0.f;
#pragma unroll
    for (int og2 = 0; og2 < 8; ++og2) v += part2[og2*264 + t];
    if (which) qcon[s*DD + t] = v * g_in[s*DD + t];
    else       vq[s*DD + t]   = v;
    if (which == 0 && t < 64) {
      float4 b4 = ((const float4*)(bq + s*DD))[t];
      float4 c4 = ((const float4*)(ck + s*DD))[t];
      float vv = wredsum(b4.x*c4.x + b4.y*c4.y + b4.z*c4.z + b4.w*c4.w);
      if (t == 0) c0[s] = vv;
    }
  }
}

// ---------------- init3: initial qg/qc from initial slots (one block per (b,s)) ----------------
__global__ __launch_bounds__(256) void k_init3(
    const float* __restrict__ slots, const float* __restrict__ g_ns,
    const float* __restrict__ b_ns, const float* __restrict__ Pg,
    const float* __restrict__ qcon, const float* __restrict__ vq,
    const float* __restrict__ c0,
    float* __restrict__ qg, float* __restrict__ qc) {
  __shared__ __align__(16) float xp[288];
  __shared__ float red[9];
  int bs = blockIdx.x;
  int s = bs & 7;
  int t = threadIdx.x, wid = t >> 6, lane = t & 63;
  float x = slots[(size_t)bs*DD + t];
  float sv = wredsum(x), sq = wredsum(x*x);
  if (lane == 0) { red[wid] = sv; red[4+wid] = sq; }
  __syncthreads();
  sv = red[0]+red[1]+red[2]+red[3];
  sq = red[4]+red[5]+red[6]+red[7];
  float mu = sv*(1.f/DD), var = sq*(1.f/DD)-mu*mu, rs = rsqrtf(var+F_LNEPS);
  float sn = (x-mu)*rs*g_ns[s*DD+t] + b_ns[s*DD+t];
  xp[xpi(t)] = sn;
  __syncthreads();
  for (int tl = 0; tl < 8; ++tl)
    gemv_tile(Pg + ((size_t)s*DD + tl*32)*DD, xp, [&](int o, float v){
      qg[(size_t)bs*DD + tl*32 + o] = v + qcon[s*DD + tl*32 + o];
    });
  float qv = wredsum(sn * vq[s*DD + t]);
  __syncthreads();
  if (lane == 0) red[wid] = qv;
  __syncthreads();
  if (t == 0) qc[bs] = red[0]+red[1]+red[2]+red[3] + c0[s];
}

// ---------------- heavy: LN(inputs) + dots + softmax(slots) + partial ax/rsum ----------------
__global__ __launch_bounds__(256) void k_dots(
    const float* __restrict__ inputs, const float* __restrict__ qg,
    const float* __restrict__ qc, float* __restrict__ axpart,
    float* __restrict__ rspart, float* __restrict__ attn_out, int write_attn) {
  __shared__ __align__(16) float qgl[SS*DD];   // 8 KB
  __shared__ __align__(16) float xt[32*260];   // 33.3 KB, padded stride 260
  __shared__ float dl[8*33];
  __shared__ float qcl[8];
  __shared__ float rsl[8];
  int t = threadIdx.x;
  int b = blockIdx.x >> 5;
  int chunk = blockIdx.x & 31;                 // 32 chunks x 64 n = 2048
  int wid = t >> 6, lane = t & 63;
  for (int i = t; i < SS*DD; i += 256) qgl[i] = qg[(size_t)b*SS*DD + i];
  if (t < 8) { qcl[t] = qc[b*8+t]; rsl[t] = 0.f; }
  int si = t >> 5, ni = t & 31;
  float axa[8] = {0.f,0.f,0.f,0.f,0.f,0.f,0.f,0.f};
  for (int tile = 0; tile < 2; ++tile) {
    int n0 = (chunk*2 + tile) * 32;
    __syncthreads();
    // stage 32 rows: wave per row, LN fused (recompute of xn)
#pragma unroll
    for (int rr = 0; rr < 8; ++rr) {
      int r = wid*8 + rr;
      const float4* src = (const float4*)(inputs + ((size_t)b*NT + n0 + r)*DD);
      float4 x = src[lane];
      float sv = wredsum(x.x + x.y + x.z + x.w);
      float sq = wredsum(x.x*x.x + x.y*x.y + x.z*x.z + x.w*x.w);
      float mu = sv*(1.f/DD), var = sq*(1.f/DD)-mu*mu, rs = rsqrtf(var+F_LNEPS);
      float4 o;
      o.x=(x.x-mu)*rs; o.y=(x.y-mu)*rs; o.z=(x.z-mu)*rs; o.w=(x.w-mu)*rs;
      *(float4*)&xt[r*260 + lane*4] = o;
    }
    __syncthreads();
    float acc = 0.f;
    {
      const float4* xr = (const float4*)&xt[ni*260];
      const float4* qr = (const float4*)&qgl[si*DD];
#pragma unroll 8
      for (int j = 0; j < 64; ++j) {
        float4 a4 = xr[j]; float4 b4 = qr[j];
        acc += a4.x*b4.x + a4.y*b4.y + a4.z*b4.z + a4.w*b4.w;
      }
    }
    float dot = (acc + qcl[si]) * F_SCALE;
    dl[si*33+ni] = dot;
    __syncthreads();
    float m = dl[ni];
#pragma unroll
    for (int ss2 = 1; ss2 < 8; ++ss2) m = fmaxf(m, dl[ss2*33+ni]);
    float den = 0.f;
#pragma unroll
    for (int ss2 = 0; ss2 < 8; ++ss2) den += __expf(dl[ss2*33+ni] - m);
    float a = __expf(dot - m) / den + F_EPS;
    __syncthreads();
    dl[si*33+ni] = a;                          // dl now holds attn_ori
    float rv = a;
#pragma unroll
    for (int mm = 16; mm > 0; mm >>= 1) rv += __shfl_xor(rv, mm, 64);
    if (ni == 0) rsl[si] += rv;
    if (write_attn) attn_out[(size_t)(b*8+si)*NT + n0 + ni] = a;
    __syncthreads();
    // ax phase: thread t = d
#pragma unroll
    for (int n = 0; n < 32; ++n) {
      float x = xt[n*260 + t];
#pragma unroll
      for (int ss2 = 0; ss2 < 8; ++ss2) axa[ss2] += dl[ss2*33+n] * x;
    }
  }
#pragma unroll
  for (int ss2 = 0; ss2 < 8; ++ss2)
    axpart[((size_t)chunk*64 + b*8 + ss2)*DD + t] = axa[ss2];
  __syncthreads();
  if (t < 8) rspart[chunk*64 + b*8 + t] = rsl[t];
}

// ---------------- fused tail: one block per (b,s) ----------------
// upd=Wv.(ax*g/r)+cv ; gh=Whh.slots+bhh ; gi=Wih.upd+bih ; GRU -> smid ;
// pre=LN(smid)*g_pf+b_pf ; h1=relu(W1.pre+b1) ; slots'=smid+W2.h1+b2 ;
// if !last: sn=LN(slots')*g_ns+b_ns ; qg=Pg.sn+qcon ; qc=sn.vq+c0
__global__ __launch_bounds__(256) void k_chain(
    float* __restrict__ slots, const float* __restrict__ axpart,
    const float* __restrict__ rspart, const float* __restrict__ g_in,
    const float* __restrict__ Wv, const float* __restrict__ cv,
    const float* __restrict__ Whh, const float* __restrict__ bhh,
    const float* __restrict__ Wih, const float* __restrict__ bih,
    const float* __restrict__ g_pf, const float* __restrict__ b_pf,
    const float* __restrict__ W1, const float* __restrict__ b1,
    const float* __restrict__ W2, const float* __restrict__ b2,
    const float* __restrict__ g_ns, const float* __restrict__ b_ns,
    const float* __restrict__ Pg, const float* __restrict__ qcon,
    const float* __restrict__ vq, const float* __restrict__ c0,
    float* __restrict__ qg, float* __restrict__ qc,
    float* __restrict__ out_slots, int last) {
  __shared__ __align__(16) float xp[288];
  __shared__ float ghl[768];
  __shared__ float gil[768];
  __shared__ float smidl[DD];
  __shared__ float bufl[DD];     // upd, then h1
  __shared__ float newsl[DD];
  __shared__ float red[9];
  int bs = blockIdx.x;           // b*8+s  (blk&7==s -> slot weights XCD-local if round-robin)
  int s = bs & 7;
  int t = threadIdx.x, wid = t >> 6, lane = t & 63;

  float slv = slots[(size_t)bs*DD + t];
  // rsum total = sum over 32 chunk partials
  if (t < 32) {
    float rv = rspart[t*64 + bs];
    rv += __shfl_xor(rv, 1, 64);
    rv += __shfl_xor(rv, 2, 64);
    rv += __shfl_xor(rv, 4, 64);
    rv += __shfl_xor(rv, 8, 64);
    rv += __shfl_xor(rv, 16, 64);
    if (t == 0) red[8] = rv;
  }
  // ax total (each thread one d)
  float axv = 0.f;
#pragma unroll 8
  for (int c = 0; c < 32; ++c) axv += axpart[((size_t)c*64 + bs)*DD + t];

  // ---- gh = Whh . slots + bhh ----
  xp[xpi(t)] = slv;
  __syncthreads();
  for (int tl = 0; tl < 24; ++tl)
    gemv_tile(Whh + ((size_t)s*768 + tl*32)*DD, xp, [&](int o, float v){
      ghl[tl*32+o] = v + bhh[s*768 + tl*32 + o]; });
  __syncthreads();

  // ---- upd = Wv . (ax * g_in / rsum) + cv ----
  float xv = axv / red[8] * g_in[s*DD + t];
  xp[xpi(t)] = xv;
  __syncthreads();
  for (int tl = 0; tl < 8; ++tl)
    gemv_tile(Wv + ((size_t)s*DD + tl*32)*DD, xp, [&](int o, float v){
      bufl[tl*32+o] = v + cv[s*DD + tl*32 + o]; });
  __syncthreads();

  // ---- gi = Wih . upd + bih ----
  float updv = bufl[t];
  xp[xpi(t)] = updv;
  __syncthreads();
  for (int tl = 0; tl < 24; ++tl)
    gemv_tile(Wih + ((size_t)s*768 + tl*32)*DD, xp, [&](int o, float v){
      gil[tl*32+o] = v + bih[s*768 + tl*32 + o]; });
  __syncthreads();

  // ---- GRU elementwise ----
  float r = sigm(gil[t] + ghl[t]);
  float z = sigm(gil[256+t] + ghl[256+t]);
  float nn2 = tanhfast(gil[512+t] + r*ghl[512+t]);
  float sm = (1.f - z)*nn2 + z*slv;
  smidl[t] = sm;

  // ---- pre = LN(smid)*g_pf + b_pf ----
  float sv = wredsum(sm), sq = wredsum(sm*sm);
  if (lane == 0) { red[wid] = sv; red[4+wid] = sq; }
  __syncthreads();
  sv = red[0]+red[1]+red[2]+red[3];
  sq = red[4]+red[5]+red[6]+red[7];
  float mu = sv*(1.f/DD), var = sq*(1.f/DD)-mu*mu, rs = rsqrtf(var+F_LNEPS);
  float pre = (sm-mu)*rs*g_pf[s*DD+t] + b_pf[s*DD+t];
  __syncthreads();
  xp[xpi(t)] = pre;
  __syncthreads();
  for (int tl = 0; tl < 8; ++tl)
    gemv_tile(W1 + ((size_t)s*HH + tl*32)*DD, xp, [&](int o, float v){
      bufl[tl*32+o] = fmaxf(v + b1[s*HH + tl*32 + o], 0.f); });
  __syncthreads();

  // ---- slots' = smid + W2 . h1 + b2 ----
  float h1v = bufl[t];
  xp[xpi(t)] = h1v;
  __syncthreads();
  for (int tl = 0; tl < 8; ++tl)
    gemv_tile(W2 + ((size_t)s*DD + tl*32)*HH, xp, [&](int o, float v){
      int d = tl*32 + o;
      float out = v + b2[s*DD + d] + smidl[d];
      size_t gidx = (size_t)bs*DD + d;
      slots[gidx] = out;
      if (last) out_slots[gidx] = out;
      newsl[d] = out; });
  __syncthreads();

  if (!last) {
    // ---- next-iter q-chain: sn = LN(slots')*g_ns+b_ns ; qg = Pg.sn+qcon ; qc ----
    float nv = newsl[t];
    float sv2 = wredsum(nv), sq2 = wredsum(nv*nv);
    if (lane == 0) { red[wid] = sv2; red[4+wid] = sq2; }
    __syncthreads();
    sv2 = red[0]+red[1]+red[2]+red[3];
    sq2 = red[4]+red[5]+red[6]+red[7];
    float mu2 = sv2*(1.f/DD), var2 = sq2*(1.f/DD)-mu2*mu2, rs2 = rsqrtf(var2+F_LNEPS);
    float sn = (nv-mu2)*rs2*g_ns[s*DD+t] + b_ns[s*DD+t];
    __syncthreads();
    xp[xpi(t)] = sn;
    __syncthreads();
    for (int tl = 0; tl < 8; ++tl)
      gemv_tile(Pg + ((size_t)s*DD + tl*32)*DD, xp, [&](int o, float v){
        qg[(size_t)bs*DD + tl*32 + o] = v + qcon[s*DD + tl*32 + o]; });
    float qv = wredsum(sn * vq[s*DD + t]);
    __syncthreads();
    if (lane == 0) red[wid] = qv;
    __syncthreads();
    if (t == 0) qc[bs] = red[0]+red[1]+red[2]+red[3] + c0[s];
  }
}

extern "C" void kernel_launch(void* const* d_in, const int* in_sizes, int n_in,
                              void* d_out, int out_size, void* d_ws, size_t ws_size,
                              hipStream_t stream) {
  (void)in_sizes; (void)n_in; (void)out_size; (void)ws_size;
  const float* inputs = (const float*)d_in[0];
  const float* noise  = (const float*)d_in[1];
  const float* smu    = (const float*)d_in[2];
  const float* slsig  = (const float*)d_in[3];
  const float* g_in   = (const float*)d_in[4];
  const float* b_in   = (const float*)d_in[5];
  const float* g_ns   = (const float*)d_in[6];
  const float* b_ns   = (const float*)d_in[7];
  const float* g_pf   = (const float*)d_in[8];
  const float* b_pf   = (const float*)d_in[9];
  const float* Wq  = (const float*)d_in[10];
  const float* bq  = (const float*)d_in[11];
  const float* Wk  = (const float*)d_in[12];
  const float* bk  = (const float*)d_in[13];
  const float* Wv  = (const float*)d_in[14];
  const float* bv  = (const float*)d_in[15];
  const float* Wih = (const float*)d_in[16];
  const float* bih = (const float*)d_in[17];
  const float* Whh = (const float*)d_in[18];
  const float* bhh = (const float*)d_in[19];
  const float* W1  = (const float*)d_in[20];
  const float* b1  = (const float*)d_in[21];
  const float* W2  = (const float*)d_in[22];
  const float* b2  = (const float*)d_in[23];

  float* ws = (float*)d_ws;
  float* slots  = ws;                 ws += BB*SS*DD;        // 16384
  float* ck     = ws;                 ws += SS*DD;           // 2048
  float* cv     = ws;                 ws += SS*DD;           // 2048
  float* qg     = ws;                 ws += BB*SS*DD;        // 16384
  float* qc     = ws;                 ws += 64;              // 64
  float* axpart = ws;                 ws += 32*64*DD;        // 524288 (2 MB)
  float* rspart = ws;                 ws += 32*64;           // 2048
  float* vq     = ws;                 ws += SS*DD;           // 2048
  float* qcon   = ws;                 ws += SS*DD;           // 2048
  float* c0     = ws;                 ws += 64;              // 8 (+pad)
  float* Pg     = ws;                 ws += SS*DD*DD;        // 524288 (2 MB)
  // total ~4.4 MB of f32 workspace

  float* out_slots = (float*)d_out;                          // f32 outputs
  float* out_attn  = out_slots + BB*SS*DD;

  k_init<<<dim3(96), dim3(256), 0, stream>>>(Wk, bk, Wv, bv, b_in, smu, slsig, noise,
                                             ck, cv, slots);
  k_init2<<<dim3(528), dim3(256), 0, stream>>>(Wq, Wk, bq, ck, g_in, Pg, vq, qcon, c0);
  k_init3<<<dim3(64), dim3(256), 0, stream>>>(slots, g_ns, b_ns, Pg, qcon, vq, c0, qg, qc);
  for (int it = 0; it < 3; ++it) {
    int last = (it == 2) ? 1 : 0;
    k_dots<<<dim3(256), dim3(256), 0, stream>>>(inputs, qg, qc, axpart, rspart,
                                                out_attn, last);
    k_chain<<<dim3(64), dim3(256), 0, stream>>>(slots, axpart, rspart, g_in,
                                                Wv, cv, Whh, bhh, Wih, bih,
                                                g_pf, b_pf, W1, b1, W2, b2,
                                                g_ns, b_ns, Pg, qcon, vq, c0,
                                                qg, qc, out_slots, last);
  }
}

// Round 8
// 332.396 us; speedup vs baseline: 1.5904x; 1.1305x over previous
//
#include <hip/hip_runtime.h>

// Slot Attention fwd, B=8 N=2048 D=256 S=8 H=256 ITERS=3.  All f32.
// Multi-kernel, 9 launches. k/v never materialized:
//   Pg[s] = diag(g_in[s]) * Wk[s]^T Wq[s]   (iteration-invariant)
//   qg[b,s] = Pg[s]*sn[b,s] + qcon[s],  qc[b,s] = sn.vq[s] + c0[s]
//   dots[b,s,n] = SCALE*( xn[b,n,:].qg[b,s,:] + qc[b,s] )
//   updates[b,s,o] = (sum_d ax*g_in*Wv)/rowsum + cv[s,o]
// xn = LN(inputs) recomputed on the fly in k_dots (never stored).
// Tail fused in k_chain: one block of 1024 threads per (b,s); 16 waves/CU for
// memory-latency hiding (round-7's 256-thread version was latency-bound at 24 GB/s/block).

#define BB 8
#define NT 2048
#define DD 256
#define SS 8
#define HH 256

static constexpr float F_EPS   = 1e-8f;
static constexpr float F_LNEPS = 1e-5f;
static constexpr float F_SCALE = 0.0625f;   // 256^-0.5

__device__ __forceinline__ float wredsum(float v) {
#pragma unroll
  for (int m = 32; m > 0; m >>= 1) v += __shfl_xor(v, m, 64);
  return v;
}
__device__ __forceinline__ float sigm(float x) { return 1.f / (1.f + __expf(-x)); }
__device__ __forceinline__ float tanhfast(float x) {
  float ax = fabsf(x);
  float e = __expf(2.f * ax);
  float t2 = 1.f - 2.f / (e + 1.f);
  return x < 0.f ? -t2 : t2;
}

// ---- sync-free GEMV tile (256 thr = 32 rows x 8 dg) ----
template <typename F>
__device__ __forceinline__ void gemv_tile(const float* __restrict__ Wrow0,
                                          const float* __restrict__ xp, F emit) {
  int t = threadIdx.x;
  int ol = t >> 3, dg = t & 7;
  const float4* wr = (const float4*)(Wrow0 + (size_t)ol*256 + dg*32);
  float acc = 0.f;
#pragma unroll
  for (int j = 0; j < 8; ++j) {
    float4 w4 = wr[j];
    float4 x4 = *(const float4*)&xp[dg*36 + 4*j];
    acc = fmaf(w4.x,x4.x, fmaf(w4.y,x4.y, fmaf(w4.z,x4.z, fmaf(w4.w,x4.w, acc))));
  }
  acc += __shfl_xor(acc, 1, 64);
  acc += __shfl_xor(acc, 2, 64);
  acc += __shfl_xor(acc, 4, 64);
  if ((t & 7) == 0) emit(ol, acc);
}
__device__ __forceinline__ int xpi(int d) { return (d>>5)*36 + (d&31); }

// ---------------- init1: ck/cv and slots ----------------
__global__ __launch_bounds__(256) void k_init(
    const float* __restrict__ Wk, const float* __restrict__ bk,
    const float* __restrict__ Wv, const float* __restrict__ bv,
    const float* __restrict__ b_in, const float* __restrict__ smu,
    const float* __restrict__ slsig, const float* __restrict__ noise,
    float* __restrict__ ck, float* __restrict__ cv, float* __restrict__ slots) {
  int blk = blockIdx.x;
  int t = threadIdx.x;
  if (blk < 32) {
    int s = blk >> 2, oq = blk & 3;
    int wid = t >> 6, lane = t & 63;
    float4 bi = ((const float4*)(b_in + s*DD))[lane];
    for (int r = 0; r < 16; ++r) {
      int o = oq*64 + wid*16 + r;
      float4 wk4 = ((const float4*)(Wk + ((size_t)s*DD + o)*DD))[lane];
      float4 wv4 = ((const float4*)(Wv + ((size_t)s*DD + o)*DD))[lane];
      float pk = wredsum(bi.x*wk4.x + bi.y*wk4.y + bi.z*wk4.z + bi.w*wk4.w);
      float pv = wredsum(bi.x*wv4.x + bi.y*wv4.y + bi.z*wv4.z + bi.w*wv4.w);
      if (lane == 0) {
        ck[s*DD+o] = pk + bk[s*DD+o];
        cv[s*DD+o] = pv + bv[s*DD+o];
      }
    }
  } else {
    int idx = (blk-32)*256 + t;       // < B*S*D
    int sd = idx & 2047;
    slots[idx] = smu[sd] + __expf(slsig[sd]) * noise[idx];
  }
}

// ---------------- init2: Pg = diag(g_in) Wk^T Wq ; vq, qcon, c0 ----------------
__global__ __launch_bounds__(256) void k_init2(
    const float* __restrict__ Wq, const float* __restrict__ Wk,
    const float* __restrict__ bq, const float* __restrict__ ck,
    const float* __restrict__ g_in,
    float* __restrict__ Pg, float* __restrict__ vq,
    float* __restrict__ qcon, float* __restrict__ c0) {
  int blk = blockIdx.x;
  int t = threadIdx.x;
  if (blk < 512) {
    __shared__ float Ak[32*33], Aq[32*33];
    int s = blk >> 6, tile = blk & 63;
    int td = tile >> 3, te = tile & 7;
    int dl = t >> 5, el = t & 31;
    float acc[4] = {0.f,0.f,0.f,0.f};
    for (int o0 = 0; o0 < DD; o0 += 32) {
      __syncthreads();
      for (int i = t; i < 1024; i += 256) {
        int o = i >> 5, c = i & 31;
        Ak[o*33+c] = Wk[((size_t)s*DD + o0+o)*DD + td*32 + c];
        Aq[o*33+c] = Wq[((size_t)s*DD + o0+o)*DD + te*32 + c];
      }
      __syncthreads();
#pragma unroll 8
      for (int o = 0; o < 32; ++o) {
        float aq = Aq[o*33+el];
#pragma unroll
        for (int j = 0; j < 4; ++j)
          acc[j] += Ak[o*33 + dl*4 + j] * aq;
      }
    }
#pragma unroll
    for (int j = 0; j < 4; ++j) {
      int d = td*32 + dl*4 + j;
      Pg[((size_t)s*DD + d)*DD + te*32 + el] = g_in[s*DD + d] * acc[j];
    }
  } else {
    // blocks 512..527: (s, which): which=0 -> vq=Wq^T ck (+c0), which=1 -> qcon=g_in.(Wk^T bq)
    __shared__ float cvec[DD];
    __shared__ float part2[8*264];
    int idx = blk - 512;
    int s = idx >> 1, which = idx & 1;
    const float* W = which ? Wk : Wq;
    const float* vec = which ? bq : ck;
    cvec[t] = vec[s*DD + t];
    __syncthreads();
    int og = t >> 5, eg = t & 31;
    float acc[8] = {0.f,0.f,0.f,0.f,0.f,0.f,0.f,0.f};
    for (int oi = 0; oi < 32; ++oi) {
      int o = og*32 + oi;
      float cv2 = cvec[o];
      const float4* wrow = (const float4*)(W + ((size_t)s*DD + o)*DD + eg*8);
      float4 w0 = wrow[0], w1 = wrow[1];
      acc[0] += w0.x*cv2; acc[1] += w0.y*cv2; acc[2] += w0.z*cv2; acc[3] += w0.w*cv2;
      acc[4] += w1.x*cv2; acc[5] += w1.y*cv2; acc[6] += w1.z*cv2; acc[7] += w1.w*cv2;
    }
#pragma unroll
    for (int j = 0; j < 8; ++j) part2[og*264 + eg*8 + j] = acc[j];
    __syncthreads();
    float v = 0.f;
#pragma unroll
    for (int og2 = 0; og2 < 8; ++og2) v += part2[og2*264 + t];
    if (which) qcon[s*DD + t] = v * g_in[s*DD + t];
    else       vq[s*DD + t]   = v;
    if (which == 0 && t < 64) {
      float4 b4 = ((const float4*)(bq + s*DD))[t];
      float4 c4 = ((const float4*)(ck + s*DD))[t];
      float vv = wredsum(b4.x*c4.x + b4.y*c4.y + b4.z*c4.z + b4.w*c4.w);
      if (t == 0) c0[s] = vv;
    }
  }
}

// ---------------- init3: initial qg/qc from initial slots ----------------
__global__ __launch_bounds__(256) void k_init3(
    const float* __restrict__ slots, const float* __restrict__ g_ns,
    const float* __restrict__ b_ns, const float* __restrict__ Pg,
    const float* __restrict__ qcon, const float* __restrict__ vq,
    const float* __restrict__ c0,
    float* __restrict__ qg, float* __restrict__ qc) {
  __shared__ __align__(16) float xp[288];
  __shared__ float red[9];
  int bs = blockIdx.x;
  int s = bs & 7;
  int t = threadIdx.x, wid = t >> 6, lane = t & 63;
  float x = slots[(size_t)bs*DD + t];
  float sv = wredsum(x), sq = wredsum(x*x);
  if (lane == 0) { red[wid] = sv; red[4+wid] = sq; }
  __syncthreads();
  sv = red[0]+red[1]+red[2]+red[3];
  sq = red[4]+red[5]+red[6]+red[7];
  float mu = sv*(1.f/DD), var = sq*(1.f/DD)-mu*mu, rs = rsqrtf(var+F_LNEPS);
  float sn = (x-mu)*rs*g_ns[s*DD+t] + b_ns[s*DD+t];
  xp[xpi(t)] = sn;
  __syncthreads();
  for (int tl = 0; tl < 8; ++tl)
    gemv_tile(Pg + ((size_t)s*DD + tl*32)*DD, xp, [&](int o, float v){
      qg[(size_t)bs*DD + tl*32 + o] = v + qcon[s*DD + tl*32 + o];
    });
  float qv = wredsum(sn * vq[s*DD + t]);
  __syncthreads();
  if (lane == 0) red[wid] = qv;
  __syncthreads();
  if (t == 0) qc[bs] = red[0]+red[1]+red[2]+red[3] + c0[s];
}

// ---------------- heavy: LN(inputs) + dots + softmax(slots) + partial ax/rsum ----------------
__global__ __launch_bounds__(256) void k_dots(
    const float* __restrict__ inputs, const float* __restrict__ qg,
    const float* __restrict__ qc, float* __restrict__ axpart,
    float* __restrict__ rspart, float* __restrict__ attn_out, int write_attn) {
  __shared__ __align__(16) float qgl[SS*DD];   // 8 KB
  __shared__ __align__(16) float xt[32*260];   // 33.3 KB, padded stride 260
  __shared__ float dl[8*33];
  __shared__ float qcl[8];
  __shared__ float rsl[8];
  int t = threadIdx.x;
  int b = blockIdx.x >> 5;
  int chunk = blockIdx.x & 31;                 // 32 chunks x 64 n = 2048
  int wid = t >> 6, lane = t & 63;
  for (int i = t; i < SS*DD; i += 256) qgl[i] = qg[(size_t)b*SS*DD + i];
  if (t < 8) { qcl[t] = qc[b*8+t]; rsl[t] = 0.f; }
  int si = t >> 5, ni = t & 31;
  float axa[8] = {0.f,0.f,0.f,0.f,0.f,0.f,0.f,0.f};
  for (int tile = 0; tile < 2; ++tile) {
    int n0 = (chunk*2 + tile) * 32;
    __syncthreads();
#pragma unroll
    for (int rr = 0; rr < 8; ++rr) {
      int r = wid*8 + rr;
      const float4* src = (const float4*)(inputs + ((size_t)b*NT + n0 + r)*DD);
      float4 x = src[lane];
      float sv = wredsum(x.x + x.y + x.z + x.w);
      float sq = wredsum(x.x*x.x + x.y*x.y + x.z*x.z + x.w*x.w);
      float mu = sv*(1.f/DD), var = sq*(1.f/DD)-mu*mu, rs = rsqrtf(var+F_LNEPS);
      float4 o;
      o.x=(x.x-mu)*rs; o.y=(x.y-mu)*rs; o.z=(x.z-mu)*rs; o.w=(x.w-mu)*rs;
      *(float4*)&xt[r*260 + lane*4] = o;
    }
    __syncthreads();
    float acc = 0.f;
    {
      const float4* xr = (const float4*)&xt[ni*260];
      const float4* qr = (const float4*)&qgl[si*DD];
#pragma unroll 8
      for (int j = 0; j < 64; ++j) {
        float4 a4 = xr[j]; float4 b4 = qr[j];
        acc += a4.x*b4.x + a4.y*b4.y + a4.z*b4.z + a4.w*b4.w;
      }
    }
    float dot = (acc + qcl[si]) * F_SCALE;
    dl[si*33+ni] = dot;
    __syncthreads();
    float m = dl[ni];
#pragma unroll
    for (int ss2 = 1; ss2 < 8; ++ss2) m = fmaxf(m, dl[ss2*33+ni]);
    float den = 0.f;
#pragma unroll
    for (int ss2 = 0; ss2 < 8; ++ss2) den += __expf(dl[ss2*33+ni] - m);
    float a = __expf(dot - m) / den + F_EPS;
    __syncthreads();
    dl[si*33+ni] = a;                          // dl now holds attn_ori
    float rv = a;
#pragma unroll
    for (int mm = 16; mm > 0; mm >>= 1) rv += __shfl_xor(rv, mm, 64);
    if (ni == 0) rsl[si] += rv;
    if (write_attn) attn_out[(size_t)(b*8+si)*NT + n0 + ni] = a;
    __syncthreads();
#pragma unroll
    for (int n = 0; n < 32; ++n) {
      float x = xt[n*260 + t];
#pragma unroll
      for (int ss2 = 0; ss2 < 8; ++ss2) axa[ss2] += dl[ss2*33+n] * x;
    }
  }
#pragma unroll
  for (int ss2 = 0; ss2 < 8; ++ss2)
    axpart[((size_t)chunk*64 + b*8 + ss2)*DD + t] = axa[ss2];
  __syncthreads();
  if (t < 8) rspart[chunk*64 + b*8 + t] = rsl[t];
}

// ---------------- fused tail: one 1024-thread block per (b,s) ----------------
// gemv tiles at 1024 thr cover 128 rows (ol = t>>3 in 0..127).
template <typename F>
__device__ __forceinline__ void gemv_tile128(const float* __restrict__ Wrow0,
                                             const float* __restrict__ xp, F emit) {
  int t = threadIdx.x;
  int ol = t >> 3, dg = t & 7;
  const float4* wr = (const float4*)(Wrow0 + (size_t)ol*256 + dg*32);
  float acc = 0.f;
#pragma unroll
  for (int j = 0; j < 8; ++j) {
    float4 w4 = wr[j];
    float4 x4 = *(const float4*)&xp[dg*36 + 4*j];
    acc = fmaf(w4.x,x4.x, fmaf(w4.y,x4.y, fmaf(w4.z,x4.z, fmaf(w4.w,x4.w, acc))));
  }
  acc += __shfl_xor(acc, 1, 64);
  acc += __shfl_xor(acc, 2, 64);
  acc += __shfl_xor(acc, 4, 64);
  if ((t & 7) == 0) emit(ol, acc);
}

__global__ __launch_bounds__(1024, 1) void k_chain(
    float* __restrict__ slots, const float* __restrict__ axpart,
    const float* __restrict__ rspart, const float* __restrict__ g_in,
    const float* __restrict__ Wv, const float* __restrict__ cv,
    const float* __restrict__ Whh, const float* __restrict__ bhh,
    const float* __restrict__ Wih, const float* __restrict__ bih,
    const float* __restrict__ g_pf, const float* __restrict__ b_pf,
    const float* __restrict__ W1, const float* __restrict__ b1,
    const float* __restrict__ W2, const float* __restrict__ b2,
    const float* __restrict__ g_ns, const float* __restrict__ b_ns,
    const float* __restrict__ Pg, const float* __restrict__ qcon,
    const float* __restrict__ vq, const float* __restrict__ c0,
    float* __restrict__ qg, float* __restrict__ qc,
    float* __restrict__ out_slots, int last) {
  __shared__ __align__(16) float xp[288];
  __shared__ float ghl[768];
  __shared__ float gil[768];
  __shared__ float smidl[DD];
  __shared__ float bufl[DD];     // upd, then h1
  __shared__ float newsl[DD];
  __shared__ float axp[4*DD];
  __shared__ float red[9];
  int bs = blockIdx.x;           // b*8+s  (blk%8==s -> slot weights XCD-local)
  int s = bs & 7;
  int t = threadIdx.x, wid = t >> 6, lane = t & 63;

  float slv = 0.f;
  if (t < 256) {
    slv = slots[(size_t)bs*DD + t];
    xp[xpi(t)] = slv;
  }
  if (t < 32) {                  // rsum total = sum over 32 chunk partials
    float rv = rspart[t*64 + bs];
    rv += __shfl_xor(rv, 1, 64);
    rv += __shfl_xor(rv, 2, 64);
    rv += __shfl_xor(rv, 4, 64);
    rv += __shfl_xor(rv, 8, 64);
    rv += __shfl_xor(rv, 16, 64);
    if (t == 0) red[8] = rv;
  }
  {                              // ax partials: 4 chunk-groups x 256 d
    int d = t & 255, cg = t >> 8;
    float axv = 0.f;
#pragma unroll
    for (int i = 0; i < 8; ++i)
      axv += axpart[((size_t)(cg*8+i)*64 + bs)*DD + d];
    axp[cg*DD + d] = axv;
  }
  __syncthreads();

  // ---- gh = Whh . slots + bhh  (6 tiles of 128) ----
  for (int tl = 0; tl < 6; ++tl)
    gemv_tile128(Whh + ((size_t)s*768 + tl*128)*DD, xp, [&](int o, float v){
      ghl[tl*128+o] = v + bhh[s*768 + tl*128 + o]; });
  __syncthreads();

  // ---- upd = Wv . (ax * g_in / rsum) + cv ----
  if (t < 256) {
    float ax = axp[t] + axp[DD+t] + axp[2*DD+t] + axp[3*DD+t];
    xp[xpi(t)] = ax / red[8] * g_in[s*DD + t];
  }
  __syncthreads();
  for (int tl = 0; tl < 2; ++tl)
    gemv_tile128(Wv + ((size_t)s*DD + tl*128)*DD, xp, [&](int o, float v){
      bufl[tl*128+o] = v + cv[s*DD + tl*128 + o]; });
  __syncthreads();

  // ---- gi = Wih . upd + bih ----
  if (t < 256) xp[xpi(t)] = bufl[t];
  __syncthreads();
  for (int tl = 0; tl < 6; ++tl)
    gemv_tile128(Wih + ((size_t)s*768 + tl*128)*DD, xp, [&](int o, float v){
      gil[tl*128+o] = v + bih[s*768 + tl*128 + o]; });
  __syncthreads();

  // ---- GRU elementwise + LN(smid) partials ----
  float sm = 0.f;
  if (t < 256) {
    float r = sigm(gil[t] + ghl[t]);
    float z = sigm(gil[256+t] + ghl[256+t]);
    float nn2 = tanhfast(gil[512+t] + r*ghl[512+t]);
    sm = (1.f - z)*nn2 + z*slv;
    smidl[t] = sm;
    float sv = wredsum(sm), sq = wredsum(sm*sm);
    if (lane == 0) { red[wid] = sv; red[4+wid] = sq; }
  }
  __syncthreads();
  if (t < 256) {
    float sv = red[0]+red[1]+red[2]+red[3];
    float sq = red[4]+red[5]+red[6]+red[7];
    float mu = sv*(1.f/DD), var = sq*(1.f/DD)-mu*mu, rs = rsqrtf(var+F_LNEPS);
    xp[xpi(t)] = (sm-mu)*rs*g_pf[s*DD+t] + b_pf[s*DD+t];
  }
  __syncthreads();
  for (int tl = 0; tl < 2; ++tl)
    gemv_tile128(W1 + ((size_t)s*HH + tl*128)*DD, xp, [&](int o, float v){
      bufl[tl*128+o] = fmaxf(v + b1[s*HH + tl*128 + o], 0.f); });
  __syncthreads();

  // ---- slots' = smid + W2 . h1 + b2 ----
  if (t < 256) xp[xpi(t)] = bufl[t];
  __syncthreads();
  for (int tl = 0; tl < 2; ++tl)
    gemv_tile128(W2 + ((size_t)s*DD + tl*128)*HH, xp, [&](int o, float v){
      int d = tl*128 + o;
      float out = v + b2[s*DD + d] + smidl[d];
      size_t gidx = (size_t)bs*DD + d;
      slots[gidx] = out;
      if (last) out_slots[gidx] = out;
      newsl[d] = out; });
  __syncthreads();

  if (!last) {
    // ---- next-iter q-chain: sn = LN(slots')*g_ns+b_ns ; qg = Pg.sn+qcon ; qc ----
    float nv = 0.f;
    if (t < 256) {
      nv = newsl[t];
      float sv2 = wredsum(nv), sq2 = wredsum(nv*nv);
      if (lane == 0) { red[wid] = sv2; red[4+wid] = sq2; }
    }
    __syncthreads();
    float sn = 0.f;
    if (t < 256) {
      float sv2 = red[0]+red[1]+red[2]+red[3];
      float sq2 = red[4]+red[5]+red[6]+red[7];
      float mu2 = sv2*(1.f/DD), var2 = sq2*(1.f/DD)-mu2*mu2, rs2 = rsqrtf(var2+F_LNEPS);
      sn = (nv-mu2)*rs2*g_ns[s*DD+t] + b_ns[s*DD+t];
      xp[xpi(t)] = sn;
    }
    __syncthreads();
    for (int tl = 0; tl < 2; ++tl)
      gemv_tile128(Pg + ((size_t)s*DD + tl*128)*DD, xp, [&](int o, float v){
        qg[(size_t)bs*DD + tl*128 + o] = v + qcon[s*DD + tl*128 + o]; });
    if (t < 256) {
      float qv = wredsum(sn * vq[s*DD + t]);
      if (lane == 0) red[wid] = qv;
    }
    __syncthreads();
    if (t == 0) qc[bs] = red[0]+red[1]+red[2]+red[3] + c0[s];
  }
}

extern "C" void kernel_launch(void* const* d_in, const int* in_sizes, int n_in,
                              void* d_out, int out_size, void* d_ws, size_t ws_size,
                              hipStream_t stream) {
  (void)in_sizes; (void)n_in; (void)out_size; (void)ws_size;
  const float* inputs = (const float*)d_in[0];
  const float* noise  = (const float*)d_in[1];
  const float* smu    = (const float*)d_in[2];
  const float* slsig  = (const float*)d_in[3];
  const float* g_in   = (const float*)d_in[4];
  const float* b_in   = (const float*)d_in[5];
  const float* g_ns   = (const float*)d_in[6];
  const float* b_ns   = (const float*)d_in[7];
  const float* g_pf   = (const float*)d_in[8];
  const float* b_pf   = (const float*)d_in[9];
  const float* Wq  = (const float*)d_in[10];
  const float* bq  = (const float*)d_in[11];
  const float* Wk  = (const float*)d_in[12];
  const float* bk  = (const float*)d_in[13];
  const float* Wv  = (const float*)d_in[14];
  const float* bv  = (const float*)d_in[15];
  const float* Wih = (const float*)d_in[16];
  const float* bih = (const float*)d_in[17];
  const float* Whh = (const float*)d_in[18];
  const float* bhh = (const float*)d_in[19];
  const float* W1  = (const float*)d_in[20];
  const float* b1  = (const float*)d_in[21];
  const float* W2  = (const float*)d_in[22];
  const float* b2  = (const float*)d_in[23];

  float* ws = (float*)d_ws;
  float* slots  = ws;                 ws += BB*SS*DD;        // 16384
  float* ck     = ws;                 ws += SS*DD;           // 2048
  float* cv     = ws;                 ws += SS*DD;           // 2048
  float* qg     = ws;                 ws += BB*SS*DD;        // 16384
  float* qc     = ws;                 ws += 64;              // 64
  float* axpart = ws;                 ws += 32*64*DD;        // 524288 (2 MB)
  float* rspart = ws;                 ws += 32*64;           // 2048
  float* vq     = ws;                 ws += SS*DD;           // 2048
  float* qcon   = ws;                 ws += SS*DD;           // 2048
  float* c0     = ws;                 ws += 64;              // 8 (+pad)
  float* Pg     = ws;                 ws += SS*DD*DD;        // 524288 (2 MB)
  // total ~4.4 MB of f32 workspace

  float* out_slots = (float*)d_out;                          // f32 outputs
  float* out_attn  = out_slots + BB*SS*DD;

  k_init<<<dim3(96), dim3(256), 0, stream>>>(Wk, bk, Wv, bv, b_in, smu, slsig, noise,
                                             ck, cv, slots);
  k_init2<<<dim3(528), dim3(256), 0, stream>>>(Wq, Wk, bq, ck, g_in, Pg, vq, qcon, c0);
  k_init3<<<dim3(64), dim3(256), 0, stream>>>(slots, g_ns, b_ns, Pg, qcon, vq, c0, qg, qc);
  for (int it = 0; it < 3; ++it) {
    int last = (it == 2) ? 1 : 0;
    k_dots<<<dim3(256), dim3(256), 0, stream>>>(inputs, qg, qc, axpart, rspart,
                                                out_attn, last);
    k_chain<<<dim3(64), dim3(1024), 0, stream>>>(slots, axpart, rspart, g_in,
                                                 Wv, cv, Whh, bhh, Wih, bih,
                                                 g_pf, b_pf, W1, b1, W2, b2,
                                                 g_ns, b_ns, Pg, qcon, vq, c0,
                                                 qg, qc, out_slots, last);
  }
}